// Round 5
// baseline (383.119 us; speedup 1.0000x reference)
//
#include <hip/hip_runtime.h>
#include <stdint.h>

typedef unsigned short ushort_t;
typedef __attribute__((ext_vector_type(8))) short bf16x8;   // 8 bf16 in 4 VGPRs
typedef __attribute__((ext_vector_type(4))) float f32x4;

__device__ __forceinline__ float bf2f(unsigned short u) {
  return __uint_as_float(((unsigned)u) << 16);
}
__device__ __forceinline__ unsigned short f2bf(float f) {
  unsigned u = __float_as_uint(f);
  u += 0x7FFFu + ((u >> 16) & 1u);   // RNE
  return (unsigned short)(u >> 16);
}

__device__ __forceinline__ void gload_lds16(const ushort_t* g, ushort_t* l) {
  __builtin_amdgcn_global_load_lds(
      (__attribute__((address_space(1))) void*)(void*)g,
      (__attribute__((address_space(3))) void*)(void*)l, 16, 0, 0);
}

// =====================================================================================
// prep: grid-x regions
//  [0,16384)        vbf' rows: [bf16(v) | 1.0 | 0 x63]  (16384 x 1088)
//  [16384,20992)    vT' tiles: vT'[b][c][n] = bf16(v[b*4096+n][c]); row1024=1; 1025..1151=0
//  [20992,29568)    weights: phW'(512x1088), gW'(512x1088), thWT'(1088x512), Ww(1024x512)
//  29568            zero stats (2048 f32)
// =====================================================================================
__global__ void prep(const float* __restrict__ v,
                     const float* __restrict__ g_w, const float* __restrict__ th_w,
                     const float* __restrict__ ph_w, const float* __restrict__ W_w,
                     const float* __restrict__ g_b, const float* __restrict__ th_b,
                     const float* __restrict__ ph_b,
                     ushort_t* __restrict__ vbfp, ushort_t* __restrict__ vTp,
                     ushort_t* __restrict__ phWp, ushort_t* __restrict__ gWp,
                     ushort_t* __restrict__ thWTp, ushort_t* __restrict__ Wwp,
                     float* __restrict__ stats) {
  const int bx = blockIdx.x;
  const int t = threadIdx.x;
  if (bx < 16384) {
    // ---- vbf' row ----
    const int row = bx;
    float4 f = *(const float4*)(v + (size_t)row * 1024 + t * 4);
    unsigned lo = (unsigned)f2bf(f.x) | (((unsigned)f2bf(f.y)) << 16);
    unsigned hi = (unsigned)f2bf(f.z) | (((unsigned)f2bf(f.w)) << 16);
    *(uint2*)(vbfp + (size_t)row * 1088 + t * 4) = make_uint2(lo, hi);
    if (t < 16) {
      uint2 pad = (t == 0) ? make_uint2(0x00003F80u, 0u) : make_uint2(0u, 0u);
      *(uint2*)(vbfp + (size_t)row * 1088 + 1024 + t * 4) = pad;
    }
  } else if (bx < 20992) {
    // ---- vT' 64x64 transpose tiles ----
    __shared__ ushort_t lds[64][65];
    const int q = bx - 16384;
    const int b = q / 1152;
    const int rem = q - b * 1152;
    const int ct = rem / 64;       // 0..17
    const int nt = rem - ct * 64;  // 0..63
    if (ct < 16) {
      const int sr = t >> 2, sc4 = (t & 3) * 16;
      const size_t src = (size_t)(b * 4096 + nt * 64 + sr) * 1024 + ct * 64 + sc4;
#pragma unroll
      for (int k = 0; k < 4; ++k) {
        float4 f = *(const float4*)(v + src + k * 4);
        lds[sr][sc4 + k * 4 + 0] = f2bf(f.x);
        lds[sr][sc4 + k * 4 + 1] = f2bf(f.y);
        lds[sr][sc4 + k * 4 + 2] = f2bf(f.z);
        lds[sr][sc4 + k * 4 + 3] = f2bf(f.w);
      }
      __syncthreads();
      const int cr = t >> 2, nb = (t & 3) * 16;
      bf16x8 o0, o1;
#pragma unroll
      for (int k = 0; k < 8; ++k) {
        o0[k] = (short)lds[nb + k][cr];
        o1[k] = (short)lds[nb + 8 + k][cr];
      }
      ushort_t* dst = vTp + ((size_t)b * 1152 + ct * 64 + cr) * 4096 + nt * 64 + nb;
      *(bf16x8*)dst = o0;
      *(bf16x8*)(dst + 8) = o1;
    } else {
      // pad rows 1024..1151: row 1024 = ones, rest zeros
      const int r = t >> 2, nb = (t & 3) * 16;
      const int grow = 1024 + (ct - 16) * 64 + r;
      const short val = (grow == 1024) ? (short)0x3F80 : (short)0;
      bf16x8 o;
#pragma unroll
      for (int k = 0; k < 8; ++k) o[k] = val;
      ushort_t* dst = vTp + ((size_t)b * 1152 + grow) * 4096 + nt * 64 + nb;
      *(bf16x8*)dst = o;
      *(bf16x8*)(dst + 8) = o;
    }
  } else if (bx < 29568) {
    const int q2 = bx - 20992;
    if (q2 < 2176) {                     // phW' (512 x 1088)
      int i = q2 * 256 + t;
      int j = i / 1088, c = i - j * 1088;
      float val = (c < 1024) ? ph_w[j * 1024 + c] : ((c == 1024) ? ph_b[j] : 0.f);
      phWp[i] = f2bf(val);
    } else if (q2 < 4352) {              // gW' (512 x 1088)
      int i = (q2 - 2176) * 256 + t;
      int j = i / 1088, c = i - j * 1088;
      float val = (c < 1024) ? g_w[j * 1024 + c] : ((c == 1024) ? g_b[j] : 0.f);
      gWp[i] = f2bf(val);
    } else if (q2 < 6528) {              // thWT' (1088 x 512): thWT'[d][j] = th_w[j][d]
      int i = (q2 - 4352) * 256 + t;
      int d = i >> 9, j = i & 511;
      float val = (d < 1024) ? th_w[j * 1024 + d] : ((d == 1024) ? th_b[j] : 0.f);
      thWTp[i] = f2bf(val);
    } else {                             // Ww (1024 x 512) native
      int i = (q2 - 6528) * 256 + t;
      Wwp[i] = f2bf(W_w[i]);
    }
  } else {
#pragma unroll
    for (int k = 0; k < 8; ++k) stats[t * 8 + k] = 0.f;
  }
}

// =====================================================================================
// G-GEMM (split-K, kc=2): Gpart[z][r][c] = sum_{k-chunk} vT'[b][r][k] * vT'[b][c][k]
// z = b*2+kc; 128x128 tile; M=N=1152, K=2048 per chunk; fp32 out.
// =====================================================================================
__global__ __launch_bounds__(256) void gemm_g(const ushort_t* __restrict__ V,
                                              float* __restrict__ Cp) {
  constexpr int FR = 4;
  __shared__ ushort_t As[128 * 64];
  __shared__ ushort_t Bs[128 * 64];
  const int tid = threadIdx.x;
  const int lane = tid & 63;
  const int wm = tid >> 7;
  const int wn = (tid >> 6) & 1;
  const int z = blockIdx.z;
  const int b = z >> 1, kc = z & 1;
  const ushort_t* Vb = V + (size_t)b * 1152 * 4096 + kc * 2048;
  float* Cb = Cp + (size_t)z * 1152 * 1152;
  const int tm0 = blockIdx.x * 128, tn0 = blockIdx.y * 128;

  f32x4 acc[FR][FR] = {};

  for (int kt = 0; kt < 2048; kt += 64) {
#pragma unroll
    for (int it = 0; it < 4; ++it) {
      int g = it * 256 + tid;
      gload_lds16(Vb + (size_t)(tm0 + (g >> 3)) * 4096 + kt + (g & 7) * 8, &As[g * 8]);
    }
#pragma unroll
    for (int it = 0; it < 4; ++it) {
      int g = it * 256 + tid;
      gload_lds16(Vb + (size_t)(tn0 + (g >> 3)) * 4096 + kt + (g & 7) * 8, &Bs[g * 8]);
    }
    __syncthreads();
#pragma unroll
    for (int kk = 0; kk < 2; ++kk) {
      bf16x8 af[FR], bfr[FR];
#pragma unroll
      for (int m = 0; m < FR; ++m)
        af[m] = *(const bf16x8*)&As[(wm * 64 + m * 16 + (lane & 15)) * 64 +
                                    kk * 32 + (lane >> 4) * 8];
#pragma unroll
      for (int n = 0; n < FR; ++n)
        bfr[n] = *(const bf16x8*)&Bs[(wn * 64 + n * 16 + (lane & 15)) * 64 +
                                     kk * 32 + (lane >> 4) * 8];
#pragma unroll
      for (int m = 0; m < FR; ++m)
#pragma unroll
        for (int n = 0; n < FR; ++n)
          acc[m][n] = __builtin_amdgcn_mfma_f32_16x16x32_bf16(af[m], bfr[n], acc[m][n], 0, 0, 0);
    }
    __syncthreads();
  }

#pragma unroll
  for (int m = 0; m < FR; ++m)
#pragma unroll
    for (int n = 0; n < FR; ++n) {
      const int col = tn0 + wn * 64 + n * 16 + (lane & 15);
#pragma unroll
      for (int r = 0; r < 4; ++r) {
        const int row = tm0 + wm * 64 + m * 16 + (lane >> 4) * 4 + r;
        Cb[(size_t)row * 1152 + col] = acc[m][n][r];
      }
    }
}

// ---------------- reduce 2 K-partials -> G' bf16 [b][1152][1152] --------------------
__global__ void reduce_g(const float* __restrict__ Gpart, ushort_t* __restrict__ Gp) {
  const int b = blockIdx.y;
  const int i4 = blockIdx.x * 256 + threadIdx.x;   // 331776 float4-groups per batch
  const float4* base = (const float4*)Gpart;
  float4 p0 = base[(size_t)(2 * b) * 331776 + i4];
  float4 p1 = base[(size_t)(2 * b + 1) * 331776 + i4];
  p0.x += p1.x; p0.y += p1.y; p0.z += p1.z; p0.w += p1.w;
  unsigned lo = (unsigned)f2bf(p0.x) | (((unsigned)f2bf(p0.y)) << 16);
  unsigned hi = (unsigned)f2bf(p0.z) | (((unsigned)f2bf(p0.w)) << 16);
  *(uint2*)(Gp + (size_t)b * 1327104 + (size_t)i4 * 4) = make_uint2(lo, hi);
}

// =====================================================================================
// generic bf16 GEMM: C[m][n] = alpha * sum_k A[m][k]*B[n][k] (+ bias[n]) (+ col stats)
// =====================================================================================
template <int BM, int BN, bool BIAS, bool STATS>
__global__ __launch_bounds__(256) void gemm_bt(
    const ushort_t* __restrict__ A, const ushort_t* __restrict__ B,
    ushort_t* __restrict__ C, const float* __restrict__ bias,
    int K, int lda, int ldb, int ldc, long sA, long sB, long sC, float alpha,
    float* __restrict__ stats_out) {
  constexpr int FR_M = BM / 32, FR_N = BN / 32;
  __shared__ ushort_t As[BM * 64];
  __shared__ ushort_t Bs[BN * 64];
  const int tid = threadIdx.x;
  const int lane = tid & 63;
  const int wm = tid >> 7;
  const int wn = (tid >> 6) & 1;
  const long b = blockIdx.z;
  A += b * sA; B += b * sB; C += b * sC;
  const int tm0 = blockIdx.x * BM, tn0 = blockIdx.y * BN;

  f32x4 acc[FR_M][FR_N] = {};

  for (int kt = 0; kt < K; kt += 64) {
#pragma unroll
    for (int it = 0; it < BM / 32; ++it) {
      int g = it * 256 + tid;
      gload_lds16(A + (long)(tm0 + (g >> 3)) * lda + kt + (g & 7) * 8, &As[g * 8]);
    }
#pragma unroll
    for (int it = 0; it < BN / 32; ++it) {
      int g = it * 256 + tid;
      gload_lds16(B + (long)(tn0 + (g >> 3)) * ldb + kt + (g & 7) * 8, &Bs[g * 8]);
    }
    __syncthreads();
#pragma unroll
    for (int kk = 0; kk < 2; ++kk) {
      bf16x8 af[FR_M], bfr[FR_N];
#pragma unroll
      for (int m = 0; m < FR_M; ++m)
        af[m] = *(const bf16x8*)&As[(wm * (BM / 2) + m * 16 + (lane & 15)) * 64 +
                                    kk * 32 + (lane >> 4) * 8];
#pragma unroll
      for (int n = 0; n < FR_N; ++n)
        bfr[n] = *(const bf16x8*)&Bs[(wn * (BN / 2) + n * 16 + (lane & 15)) * 64 +
                                     kk * 32 + (lane >> 4) * 8];
#pragma unroll
      for (int m = 0; m < FR_M; ++m)
#pragma unroll
        for (int n = 0; n < FR_N; ++n)
          acc[m][n] = __builtin_amdgcn_mfma_f32_16x16x32_bf16(af[m], bfr[n], acc[m][n], 0, 0, 0);
    }
    __syncthreads();
  }

#pragma unroll
  for (int n = 0; n < FR_N; ++n) {
    const int col = tn0 + wn * (BN / 2) + n * 16 + (lane & 15);
    const float bv = BIAS ? bias[col] : 0.0f;
    float s = 0.f, s2 = 0.f;
#pragma unroll
    for (int m = 0; m < FR_M; ++m) {
#pragma unroll
      for (int r = 0; r < 4; ++r) {
        const int row = tm0 + wm * (BM / 2) + m * 16 + (lane >> 4) * 4 + r;
        float val = alpha * acc[m][n][r] + bv;
        C[(long)row * ldc + col] = f2bf(val);
        if (STATS) { s += val; s2 += val * val; }
      }
    }
    if (STATS) {
      s  += __shfl_xor(s, 16);  s  += __shfl_xor(s, 32);
      s2 += __shfl_xor(s2, 16); s2 += __shfl_xor(s2, 32);
      if ((lane >> 4) == 0) {
        atomicAdd(&stats_out[col], s);
        atomicAdd(&stats_out[1024 + col], s2);
      }
    }
  }
}

// ---------------- apply BN (inline finalize) + residual ------------------------------
__global__ void bn_apply(const ushort_t* __restrict__ Wy, const ushort_t* __restrict__ vbfp,
                         const float* __restrict__ stats, const float* __restrict__ gamma,
                         const float* __restrict__ beta, float* __restrict__ out) {
  __shared__ float scsh[2048];
  const int t = threadIdx.x;
#pragma unroll
  for (int k = 0; k < 4; ++k) {
    int c = t * 4 + k;
    float mean = stats[c] * (1.0f / 16384.0f);
    float var = stats[1024 + c] * (1.0f / 16384.0f) - mean * mean;
    float sc = gamma[c] * rsqrtf(var + 1e-5f);
    scsh[c] = sc;
    scsh[1024 + c] = beta[c] - mean * sc;
  }
  __syncthreads();
  size_t gi = ((size_t)blockIdx.x * 256 + t) * 8;
  const int row = (int)(gi >> 10);
  const int col = (int)(gi & 1023);
  bf16x8 w = *(const bf16x8*)(Wy + gi);
  bf16x8 vv = *(const bf16x8*)(vbfp + (size_t)row * 1088 + col);
  float4 o0, o1;
  o0.x = bf2f((unsigned short)w[0]) * scsh[col + 0] + scsh[1024 + col + 0] + bf2f((unsigned short)vv[0]);
  o0.y = bf2f((unsigned short)w[1]) * scsh[col + 1] + scsh[1024 + col + 1] + bf2f((unsigned short)vv[1]);
  o0.z = bf2f((unsigned short)w[2]) * scsh[col + 2] + scsh[1024 + col + 2] + bf2f((unsigned short)vv[2]);
  o0.w = bf2f((unsigned short)w[3]) * scsh[col + 3] + scsh[1024 + col + 3] + bf2f((unsigned short)vv[3]);
  o1.x = bf2f((unsigned short)w[4]) * scsh[col + 4] + scsh[1024 + col + 4] + bf2f((unsigned short)vv[4]);
  o1.y = bf2f((unsigned short)w[5]) * scsh[col + 5] + scsh[1024 + col + 5] + bf2f((unsigned short)vv[5]);
  o1.z = bf2f((unsigned short)w[6]) * scsh[col + 6] + scsh[1024 + col + 6] + bf2f((unsigned short)vv[6]);
  o1.w = bf2f((unsigned short)w[7]) * scsh[col + 7] + scsh[1024 + col + 7] + bf2f((unsigned short)vv[7]);
  *(float4*)(out + gi) = o0;
  *(float4*)(out + gi + 4) = o1;
}

extern "C" void kernel_launch(void* const* d_in, const int* in_sizes, int n_in,
                              void* d_out, int out_size, void* d_ws, size_t ws_size,
                              hipStream_t stream) {
  const float* v     = (const float*)d_in[0];
  const float* g_w   = (const float*)d_in[1];
  const float* g_b   = (const float*)d_in[2];
  const float* th_w  = (const float*)d_in[3];
  const float* th_b  = (const float*)d_in[4];
  const float* ph_w  = (const float*)d_in[5];
  const float* ph_b  = (const float*)d_in[6];
  const float* W_w   = (const float*)d_in[7];
  const float* W_b   = (const float*)d_in[8];
  const float* gamma = (const float*)d_in[9];
  const float* beta  = (const float*)d_in[10];
  float* out = (float*)d_out;
  char* ws = (char*)d_ws;

  const size_t MB = 1024 * 1024;
  // Workspace map (max ~130 MB, within validated envelope):
  //  [0,36)    vbf' 16384x1088 bf16 (35.7MB)            prep -> Wy-GEMM, bn_apply
  //  [36,72)   vT'  4x1152x4096 bf16 (36MB)             prep -> G        } Wy overlays @36 after G
  //  [72,113)  Gpart 8x1152^2 fp32 (40.5MB)             G -> reduce      } chain overlays after
  //    [72,77)  T1 4x512x1088 bf16   [77,79) M 4x512^2  [80,84) ZT 4x1024x512  [85,94) ZZT' 4x1024x1088
  //  [113,124) G' 4x1152^2 bf16 (10.1MB)
  //  [124,130) weights: phW' gW' thWT' Ww
  //  [130,..)  stats
  ushort_t* vbfp  = (ushort_t*)(ws);
  ushort_t* vTp   = (ushort_t*)(ws + 36 * MB);
  ushort_t* Wyp   = (ushort_t*)(ws + 36 * MB);          // overlays vT' after G-GEMM
  float*    Gpart = (float*)(ws + 72 * MB);
  ushort_t* T1p   = (ushort_t*)(ws + 72 * MB);          // overlays Gpart after reduce_g
  ushort_t* Mp    = (ushort_t*)(ws + 77 * MB);
  ushort_t* ZTp   = (ushort_t*)(ws + 80 * MB);
  ushort_t* ZZTp  = (ushort_t*)(ws + 85 * MB);
  ushort_t* Gp    = (ushort_t*)(ws + 113 * MB);
  ushort_t* phWp  = (ushort_t*)(ws + 124 * MB);
  ushort_t* gWp   = (ushort_t*)(ws + 125 * MB + 512 * 1024);
  ushort_t* thWTp = (ushort_t*)(ws + 127 * MB);
  ushort_t* Wwp   = (ushort_t*)(ws + 128 * MB + 512 * 1024);
  float* stats    = (float*)(ws + 130 * MB);

  // 1. prep: casts, v-transpose (+ones/zero pad), weight packing, stats zero
  prep<<<29569, 256, 0, stream>>>(v, g_w, th_w, ph_w, W_w, g_b, th_b, ph_b,
                                  vbfp, vTp, phWp, gWp, thWTp, Wwp, stats);

  // 2. G' = v'^T v' (1152x1152 per batch incl. bias row/col), split-K x2
  gemm_g<<<dim3(9, 9, 8), 256, 0, stream>>>(vTp, Gpart);
  reduce_g<<<dim3(1296, 4), 256, 0, stream>>>(Gpart, Gp);

  // 3. T1[j][d] = sum_c phW'[j][c] * G'[d][c]        (512 x 1088, K=1088)
  gemm_bt<64, 64, false, false><<<dim3(8, 17, 4), 256, 0, stream>>>(
      phWp, Gp, T1p, nullptr, 1088, 1088, 1152, 1088,
      0L, 1152L * 1152, 512L * 1088, 1.0f, nullptr);

  // 4. M[j][i] = (1/4096) sum_d T1[j][d] * gW'[i][d] (512 x 512, K=1088)
  gemm_bt<64, 64, false, false><<<dim3(8, 8, 4), 256, 0, stream>>>(
      T1p, gWp, Mp, nullptr, 1088, 1088, 1088, 512,
      512L * 1088, 0L, 512L * 512, 1.0f / 4096.0f, nullptr);

  // 5. ZT[c][j] = sum_i Ww[c][i] * M[j][i]           (1024 x 512, K=512)
  gemm_bt<64, 64, false, false><<<dim3(16, 8, 4), 256, 0, stream>>>(
      Wwp, Mp, ZTp, nullptr, 512, 512, 512, 512,
      0L, 512L * 512, 1024L * 512, 1.0f, nullptr);

  // 6. ZZT'[c][d] = sum_j ZT[c][j] * thWT'[d][j]     (1024 x 1088, K=512)
  gemm_bt<64, 64, false, false><<<dim3(16, 17, 4), 256, 0, stream>>>(
      ZTp, thWTp, ZZTp, nullptr, 512, 512, 512, 1088,
      1024L * 512, 0L, 1024L * 1088, 1.0f, nullptr);

  // 7. Wy[n][c] = sum_d v'[n][d] * ZZT'[c][d] + Wb[c]  (+fused BN stats), K=1088
  gemm_bt<128, 128, true, true><<<dim3(32, 8, 4), 256, 0, stream>>>(
      vbfp, ZZTp, Wyp, W_b, 1088, 1088, 1088, 1024,
      4096L * 1088, 1024L * 1088, 4096L * 1024, 1.0f, stats);

  // 8. BN finalize (inline) + apply + residual
  bn_apply<<<8192, 256, 0, stream>>>(Wyp, vbfp, stats, gamma, beta, out);
}

// Round 6
// 316.192 us; speedup vs baseline: 1.2117x; 1.2117x over previous
//
#include <hip/hip_runtime.h>
#include <stdint.h>

typedef unsigned short ushort_t;
typedef __attribute__((ext_vector_type(8))) short bf16x8;   // 8 bf16 in 4 VGPRs
typedef __attribute__((ext_vector_type(4))) float f32x4;

__device__ __forceinline__ float bf2f(unsigned short u) {
  return __uint_as_float(((unsigned)u) << 16);
}
__device__ __forceinline__ unsigned short f2bf(float f) {
  unsigned u = __float_as_uint(f);
  u += 0x7FFFu + ((u >> 16) & 1u);   // RNE
  return (unsigned short)(u >> 16);
}

__device__ __forceinline__ void gload_lds16(const ushort_t* g, ushort_t* l) {
  __builtin_amdgcn_global_load_lds(
      (__attribute__((address_space(1))) void*)(void*)g,
      (__attribute__((address_space(3))) void*)(void*)l, 16, 0, 0);
}

// ------------- merged: cast v->bf16 [0,16384) + pack weights [16384,24576) + stats-zero
__global__ void prep(const float* __restrict__ v,
                     const float* __restrict__ g_w, const float* __restrict__ th_w,
                     const float* __restrict__ ph_w, const float* __restrict__ W_w,
                     const float* __restrict__ g_b, const float* __restrict__ th_b,
                     const float* __restrict__ ph_b,
                     ushort_t* __restrict__ vbf,
                     ushort_t* __restrict__ Wcat, ushort_t* __restrict__ Ww,
                     float* __restrict__ bias_cat, float* __restrict__ stats) {
  if (blockIdx.x < 16384) {
    size_t i = ((size_t)blockIdx.x * 256 + threadIdx.x) * 4;
    float4 f = *(const float4*)(v + i);
    unsigned lo = (unsigned)f2bf(f.x) | (((unsigned)f2bf(f.y)) << 16);
    unsigned hi = (unsigned)f2bf(f.z) | (((unsigned)f2bf(f.w)) << 16);
    *(uint2*)(vbf + i) = make_uint2(lo, hi);
  } else if (blockIdx.x < 24576) {
    int i = (blockIdx.x - 16384) * 256 + threadIdx.x;
    if (i < 1536 * 1024) {
      int r = i >> 10;
      float val;
      if (r < 512)        val = g_w[i];
      else if (r < 1024)  val = th_w[i - 512 * 1024];
      else                val = ph_w[i - 1024 * 1024];
      Wcat[i] = f2bf(val);
    } else {
      int j = i - 1536 * 1024;
      Ww[j] = f2bf(W_w[j]);   // W_w is (1024, 512) row-major == B^T layout
    }
    if (i < 512)        bias_cat[i] = g_b[i];
    else if (i < 1024)  bias_cat[i] = th_b[i - 512];
    else if (i < 1536)  bias_cat[i] = ph_b[i - 1024];
  } else {
#pragma unroll
    for (int k = 0; k < 8; ++k) stats[threadIdx.x * 8 + k] = 0.f;
  }
}

// ---------------- GEMM1: P-projections with layout-split epilogue -------------------
// A = vbf (16384x1024), B = Wcat^T (1536x1024). Output column ranges:
//   [0,512)     -> gvT[b][c][n]       (transposed; LDS-bounce coalesced)
//   [512,1024)  -> th[n][c-512]       (row-major, ld=512)
//   [1024,1536) -> phT[b][c-1024][n]  (transposed; LDS-bounce coalesced)
__global__ __launch_bounds__(256) void gemm1(
    const ushort_t* __restrict__ A, const ushort_t* __restrict__ B,
    ushort_t* __restrict__ gvT, ushort_t* __restrict__ th, ushort_t* __restrict__ phT,
    const float* __restrict__ bias) {
  constexpr int BM = 128, BN = 128, FR_M = 4, FR_N = 4;
  __shared__ ushort_t sh[BM * 64 + BN * 64];   // As | Bs ; aliased as Tt in epilogue
  ushort_t* As = sh;
  ushort_t* Bs = sh + BM * 64;
  const int tid = threadIdx.x;
  const int lane = tid & 63;
  const int wm = tid >> 7;
  const int wn = (tid >> 6) & 1;
  const int tm0 = blockIdx.x * BM, tn0 = blockIdx.y * BN;

  f32x4 acc[FR_M][FR_N] = {};

  for (int kt = 0; kt < 1024; kt += 64) {
#pragma unroll
    for (int it = 0; it < 4; ++it) {
      int g = it * 256 + tid;
      gload_lds16(A + (long)(tm0 + (g >> 3)) * 1024 + kt + (g & 7) * 8, &As[g * 8]);
    }
#pragma unroll
    for (int it = 0; it < 4; ++it) {
      int g = it * 256 + tid;
      gload_lds16(B + (long)(tn0 + (g >> 3)) * 1024 + kt + (g & 7) * 8, &Bs[g * 8]);
    }
    __syncthreads();
#pragma unroll
    for (int kk = 0; kk < 2; ++kk) {
      bf16x8 af[FR_M], bfr[FR_N];
#pragma unroll
      for (int m = 0; m < FR_M; ++m)
        af[m] = *(const bf16x8*)&As[(wm * 64 + m * 16 + (lane & 15)) * 64 +
                                    kk * 32 + (lane >> 4) * 8];
#pragma unroll
      for (int n = 0; n < FR_N; ++n)
        bfr[n] = *(const bf16x8*)&Bs[(wn * 64 + n * 16 + (lane & 15)) * 64 +
                                     kk * 32 + (lane >> 4) * 8];
#pragma unroll
      for (int m = 0; m < FR_M; ++m)
#pragma unroll
        for (int n = 0; n < FR_N; ++n)
          acc[m][n] = __builtin_amdgcn_mfma_f32_16x16x32_bf16(af[m], bfr[n], acc[m][n], 0, 0, 0);
    }
    __syncthreads();
  }

  if (tn0 >= 512 && tn0 < 1024) {
    // th: row-major direct store
#pragma unroll
    for (int n = 0; n < FR_N; ++n) {
      const int gcol = tn0 + wn * 64 + n * 16 + (lane & 15);
      const float bv = bias[gcol];
      const int col = gcol - 512;
#pragma unroll
      for (int m = 0; m < FR_M; ++m) {
#pragma unroll
        for (int r = 0; r < 4; ++r) {
          const int row = tm0 + wm * 64 + m * 16 + (lane >> 4) * 4 + r;
          th[(size_t)row * 512 + col] = f2bf(acc[m][n][r] + bv);
        }
      }
    }
  } else {
    // transposed outputs via LDS bounce: two passes of 64 columns each.
    ushort_t* T = (tn0 < 512) ? gvT : phT;
    const int coff = (tn0 < 512) ? 0 : 1024;
    const int cbase = tn0 - coff;              // 0,128,256,384
    const int bq = tm0 >> 12;                  // batch (tiles never straddle 4096)
    const int npb = tm0 & 4095;
    ushort_t* Tt = sh;                          // 64*136 = 8704 el <= 16384
#pragma unroll
    for (int p = 0; p < 2; ++p) {
      __syncthreads();   // sh free (post k-loop barrier / previous pass readout)
#pragma unroll
      for (int q = 0; q < 2; ++q) {
        const int n = 2 * p + q;
        const float bv = bias[tn0 + wn * 64 + n * 16 + (lane & 15)];
        const int lc = wn * 32 + q * 16 + (lane & 15);
#pragma unroll
        for (int m = 0; m < FR_M; ++m) {
          const int lrow = wm * 64 + m * 16 + (lane >> 4) * 4;
          unsigned lo = (unsigned)f2bf(acc[m][n][0] + bv) |
                        (((unsigned)f2bf(acc[m][n][1] + bv)) << 16);
          unsigned hi = (unsigned)f2bf(acc[m][n][2] + bv) |
                        (((unsigned)f2bf(acc[m][n][3] + bv)) << 16);
          *(uint2*)&Tt[lc * 136 + lrow] = make_uint2(lo, hi);
        }
      }
      __syncthreads();
      // writeout: 64 cols x 128 rows; 16 lanes cover 256B contiguous per col
#pragma unroll
      for (int s = 0; s < 4; ++s) {
        const int lc = (tid >> 4) + s * 16;
        const int seg = tid & 15;
        bf16x8 val = *(const bf16x8*)&Tt[lc * 136 + seg * 8];
        const int colc = cbase + (lc >> 5) * 64 + p * 32 + (lc & 31);
        *(bf16x8*)(T + ((size_t)(bq * 512 + colc)) * 4096 + npb + seg * 8) = val;
      }
    }
  }
}

// ---------------- bf16 GEMM: C[m][n] = alpha * sum_k A[m][k]*BT[n][k] (+ bias[n]) ---
template <int BM, int BN, bool BIAS, bool STATS>
__global__ __launch_bounds__(256) void gemm_bt(
    const ushort_t* __restrict__ A, const ushort_t* __restrict__ B,
    ushort_t* __restrict__ C, const float* __restrict__ bias,
    int K, int lda, int ldb, int ldc, long sA, long sB, long sC, float alpha,
    float* __restrict__ stats_out) {
  constexpr int FR_M = BM / 32, FR_N = BN / 32;
  __shared__ ushort_t As[BM * 64];
  __shared__ ushort_t Bs[BN * 64];
  const int tid = threadIdx.x;
  const int lane = tid & 63;
  const int wm = tid >> 7;
  const int wn = (tid >> 6) & 1;
  const long b = blockIdx.z;
  A += b * sA; B += b * sB; C += b * sC;
  const int tm0 = blockIdx.x * BM, tn0 = blockIdx.y * BN;

  f32x4 acc[FR_M][FR_N] = {};

  for (int kt = 0; kt < K; kt += 64) {
#pragma unroll
    for (int it = 0; it < BM / 32; ++it) {
      int g = it * 256 + tid;
      gload_lds16(A + (long)(tm0 + (g >> 3)) * lda + kt + (g & 7) * 8, &As[g * 8]);
    }
#pragma unroll
    for (int it = 0; it < BN / 32; ++it) {
      int g = it * 256 + tid;
      gload_lds16(B + (long)(tn0 + (g >> 3)) * ldb + kt + (g & 7) * 8, &Bs[g * 8]);
    }
    __syncthreads();
#pragma unroll
    for (int kk = 0; kk < 2; ++kk) {
      bf16x8 af[FR_M], bfr[FR_N];
#pragma unroll
      for (int m = 0; m < FR_M; ++m)
        af[m] = *(const bf16x8*)&As[(wm * (BM / 2) + m * 16 + (lane & 15)) * 64 +
                                    kk * 32 + (lane >> 4) * 8];
#pragma unroll
      for (int n = 0; n < FR_N; ++n)
        bfr[n] = *(const bf16x8*)&Bs[(wn * (BN / 2) + n * 16 + (lane & 15)) * 64 +
                                     kk * 32 + (lane >> 4) * 8];
#pragma unroll
      for (int m = 0; m < FR_M; ++m)
#pragma unroll
        for (int n = 0; n < FR_N; ++n)
          acc[m][n] = __builtin_amdgcn_mfma_f32_16x16x32_bf16(af[m], bfr[n], acc[m][n], 0, 0, 0);
    }
    __syncthreads();
  }

#pragma unroll
  for (int n = 0; n < FR_N; ++n) {
    const int col = tn0 + wn * (BN / 2) + n * 16 + (lane & 15);
    const float bv = BIAS ? bias[col] : 0.0f;
    float s = 0.f, s2 = 0.f;
#pragma unroll
    for (int m = 0; m < FR_M; ++m) {
#pragma unroll
      for (int r = 0; r < 4; ++r) {
        const int row = tm0 + wm * (BM / 2) + m * 16 + (lane >> 4) * 4 + r;
        float val = alpha * acc[m][n][r] + bv;
        C[(long)row * ldc + col] = f2bf(val);
        if (STATS) { s += val; s2 += val * val; }
      }
    }
    if (STATS) {
      s  += __shfl_xor(s, 16);  s  += __shfl_xor(s, 32);
      s2 += __shfl_xor(s2, 16); s2 += __shfl_xor(s2, 32);
      if ((lane >> 4) == 0) {
        atomicAdd(&stats_out[col], s);
        atomicAdd(&stats_out[1024 + col], s2);
      }
    }
  }
}

// ---------------- split-K GEMM2: Mpart[b*4+kc][i][j] (fp32, pre-scaled 1/4096) ------
__global__ __launch_bounds__(256) void gemm_splitk(
    const ushort_t* __restrict__ A, const ushort_t* __restrict__ B,
    float* __restrict__ Cp) {
  constexpr int BM = 128, BN = 64, FR_M = 4, FR_N = 2;
  __shared__ ushort_t As[BM * 64];
  __shared__ ushort_t Bs[BN * 64];
  const int tid = threadIdx.x;
  const int lane = tid & 63;
  const int wm = tid >> 7;
  const int wn = (tid >> 6) & 1;
  const int b = blockIdx.z >> 2, kc = blockIdx.z & 3;
  const ushort_t* Ab = A + (size_t)b * 512 * 4096 + kc * 1024;
  const ushort_t* Bb = B + (size_t)b * 512 * 4096 + kc * 1024;
  float* Cb = Cp + (size_t)blockIdx.z * 512 * 512;
  const int tm0 = blockIdx.x * BM, tn0 = blockIdx.y * BN;

  f32x4 acc[FR_M][FR_N] = {};

  for (int kt = 0; kt < 1024; kt += 64) {
#pragma unroll
    for (int it = 0; it < BM / 32; ++it) {
      int g = it * 256 + tid;
      gload_lds16(Ab + (long)(tm0 + (g >> 3)) * 4096 + kt + (g & 7) * 8, &As[g * 8]);
    }
#pragma unroll
    for (int it = 0; it < BN / 32; ++it) {
      int g = it * 256 + tid;
      gload_lds16(Bb + (long)(tn0 + (g >> 3)) * 4096 + kt + (g & 7) * 8, &Bs[g * 8]);
    }
    __syncthreads();
#pragma unroll
    for (int kk = 0; kk < 2; ++kk) {
      bf16x8 af[FR_M], bfr[FR_N];
#pragma unroll
      for (int m = 0; m < FR_M; ++m)
        af[m] = *(const bf16x8*)&As[(wm * (BM / 2) + m * 16 + (lane & 15)) * 64 +
                                    kk * 32 + (lane >> 4) * 8];
#pragma unroll
      for (int n = 0; n < FR_N; ++n)
        bfr[n] = *(const bf16x8*)&Bs[(wn * (BN / 2) + n * 16 + (lane & 15)) * 64 +
                                     kk * 32 + (lane >> 4) * 8];
#pragma unroll
      for (int m = 0; m < FR_M; ++m)
#pragma unroll
        for (int n = 0; n < FR_N; ++n)
          acc[m][n] = __builtin_amdgcn_mfma_f32_16x16x32_bf16(af[m], bfr[n], acc[m][n], 0, 0, 0);
    }
    __syncthreads();
  }

#pragma unroll
  for (int m = 0; m < FR_M; ++m)
#pragma unroll
    for (int n = 0; n < FR_N; ++n) {
      const int col = tn0 + wn * (BN / 2) + n * 16 + (lane & 15);
#pragma unroll
      for (int r = 0; r < 4; ++r) {
        const int row = tm0 + wm * (BM / 2) + m * 16 + (lane >> 4) * 4 + r;
        Cb[(long)row * 512 + col] = (1.0f / 4096.0f) * acc[m][n][r];
      }
    }
}

// ---------------- Q-GEMM with fused partial-reduce on the B operand -----------------
// Q[b][c][j] = sum_i Ww[c][i] * M[b][j][i],  M = sum of 4 fp32 partials (bf16-rounded)
__global__ __launch_bounds__(256) void gemm_q(
    const ushort_t* __restrict__ Ww, const float* __restrict__ Mpart,
    ushort_t* __restrict__ Qb) {
  __shared__ ushort_t As[64 * 64];
  __shared__ ushort_t Bs[64 * 64];
  const int tid = threadIdx.x;
  const int lane = tid & 63;
  const int wm = tid >> 7;
  const int wn = (tid >> 6) & 1;
  const int b = blockIdx.z;
  const float* Mb4 = Mpart + (size_t)b * 4 * 262144;
  ushort_t* Cb = Qb + (size_t)b * 1024 * 512;
  const int tm0 = blockIdx.x * 64, tn0 = blockIdx.y * 64;

  f32x4 acc[2][2] = {};

  for (int kt = 0; kt < 512; kt += 64) {
#pragma unroll
    for (int it = 0; it < 2; ++it) {
      int g = it * 256 + tid;
      gload_lds16(Ww + (long)(tm0 + (g >> 3)) * 512 + kt + (g & 7) * 8, &As[g * 8]);
    }
#pragma unroll
    for (int it = 0; it < 2; ++it) {
      int g = it * 256 + tid;
      const int jr = g >> 3, ioff = (g & 7) * 8;
      const float* src = Mb4 + (size_t)(tn0 + jr) * 512 + kt + ioff;
      float4 s0 = *(const float4*)(src);
      float4 s1 = *(const float4*)(src + 4);
#pragma unroll
      for (int p = 1; p < 4; ++p) {
        float4 t0 = *(const float4*)(src + (size_t)p * 262144);
        float4 t1 = *(const float4*)(src + (size_t)p * 262144 + 4);
        s0.x += t0.x; s0.y += t0.y; s0.z += t0.z; s0.w += t0.w;
        s1.x += t1.x; s1.y += t1.y; s1.z += t1.z; s1.w += t1.w;
      }
      bf16x8 o;
      o[0] = (short)f2bf(s0.x); o[1] = (short)f2bf(s0.y);
      o[2] = (short)f2bf(s0.z); o[3] = (short)f2bf(s0.w);
      o[4] = (short)f2bf(s1.x); o[5] = (short)f2bf(s1.y);
      o[6] = (short)f2bf(s1.z); o[7] = (short)f2bf(s1.w);
      *(bf16x8*)&Bs[g * 8] = o;
    }
    __syncthreads();
#pragma unroll
    for (int kk = 0; kk < 2; ++kk) {
      bf16x8 af[2], bfr[2];
#pragma unroll
      for (int m = 0; m < 2; ++m)
        af[m] = *(const bf16x8*)&As[(wm * 32 + m * 16 + (lane & 15)) * 64 +
                                    kk * 32 + (lane >> 4) * 8];
#pragma unroll
      for (int n = 0; n < 2; ++n)
        bfr[n] = *(const bf16x8*)&Bs[(wn * 32 + n * 16 + (lane & 15)) * 64 +
                                     kk * 32 + (lane >> 4) * 8];
#pragma unroll
      for (int m = 0; m < 2; ++m)
#pragma unroll
        for (int n = 0; n < 2; ++n)
          acc[m][n] = __builtin_amdgcn_mfma_f32_16x16x32_bf16(af[m], bfr[n], acc[m][n], 0, 0, 0);
    }
    __syncthreads();
  }

#pragma unroll
  for (int m = 0; m < 2; ++m)
#pragma unroll
    for (int n = 0; n < 2; ++n) {
      const int col = tn0 + wn * 32 + n * 16 + (lane & 15);
#pragma unroll
      for (int r = 0; r < 4; ++r) {
        const int row = tm0 + wm * 32 + m * 16 + (lane >> 4) * 4 + r;
        Cb[(long)row * 512 + col] = f2bf(acc[m][n][r]);
      }
    }
}

// ---------------- apply BN (inline finalize) + residual (bf16 v) --------------------
__global__ void bn_apply(const ushort_t* __restrict__ Wy, const ushort_t* __restrict__ vbf,
                         const float* __restrict__ stats, const float* __restrict__ gamma,
                         const float* __restrict__ beta, float* __restrict__ out) {
  __shared__ float scsh[2048];
  const int t = threadIdx.x;
#pragma unroll
  for (int k = 0; k < 4; ++k) {
    int c = t * 4 + k;
    float mean = stats[c] * (1.0f / 16384.0f);
    float var = stats[1024 + c] * (1.0f / 16384.0f) - mean * mean;
    float sc = gamma[c] * rsqrtf(var + 1e-5f);
    scsh[c] = sc;
    scsh[1024 + c] = beta[c] - mean * sc;
  }
  __syncthreads();
  size_t i = ((size_t)blockIdx.x * 256 + t) * 8;
  int c0 = (int)(i & 1023);
  bf16x8 w = *(const bf16x8*)(Wy + i);
  bf16x8 vv = *(const bf16x8*)(vbf + i);
  float4 o0, o1;
  o0.x = bf2f((unsigned short)w[0]) * scsh[c0 + 0] + scsh[1024 + c0 + 0] + bf2f((unsigned short)vv[0]);
  o0.y = bf2f((unsigned short)w[1]) * scsh[c0 + 1] + scsh[1024 + c0 + 1] + bf2f((unsigned short)vv[1]);
  o0.z = bf2f((unsigned short)w[2]) * scsh[c0 + 2] + scsh[1024 + c0 + 2] + bf2f((unsigned short)vv[2]);
  o0.w = bf2f((unsigned short)w[3]) * scsh[c0 + 3] + scsh[1024 + c0 + 3] + bf2f((unsigned short)vv[3]);
  o1.x = bf2f((unsigned short)w[4]) * scsh[c0 + 4] + scsh[1024 + c0 + 4] + bf2f((unsigned short)vv[4]);
  o1.y = bf2f((unsigned short)w[5]) * scsh[c0 + 5] + scsh[1024 + c0 + 5] + bf2f((unsigned short)vv[5]);
  o1.z = bf2f((unsigned short)w[6]) * scsh[c0 + 6] + scsh[1024 + c0 + 6] + bf2f((unsigned short)vv[6]);
  o1.w = bf2f((unsigned short)w[7]) * scsh[c0 + 7] + scsh[1024 + c0 + 7] + bf2f((unsigned short)vv[7]);
  *(float4*)(out + i) = o0;
  *(float4*)(out + i + 4) = o1;
}

extern "C" void kernel_launch(void* const* d_in, const int* in_sizes, int n_in,
                              void* d_out, int out_size, void* d_ws, size_t ws_size,
                              hipStream_t stream) {
  const float* v     = (const float*)d_in[0];
  const float* g_w   = (const float*)d_in[1];
  const float* g_b   = (const float*)d_in[2];
  const float* th_w  = (const float*)d_in[3];
  const float* th_b  = (const float*)d_in[4];
  const float* ph_w  = (const float*)d_in[5];
  const float* ph_b  = (const float*)d_in[6];
  const float* W_w   = (const float*)d_in[7];
  const float* W_b   = (const float*)d_in[8];
  const float* gamma = (const float*)d_in[9];
  const float* beta  = (const float*)d_in[10];
  float* out = (float*)d_out;
  char* ws = (char*)d_ws;

  const size_t MB = 1024 * 1024;
  // Lifetime-packed plan (max ~107 MB):
  //  [0,32)   vbf          prep -> gemm1, bn_apply
  //  [32,48)  th           gemm1 -> gemm3'
  //  [48,64)  gvT          gemm1 -> splitk   }  overlaid by Wy after splitk
  //  [64,80)  phT          gemm1 -> splitk   }
  //  [80,96)  Mpart        splitk -> gemm_q (fused reduce)
  //  [98,102) Qb, [102,105) Wcat, [105,106) Wwb, [106,...) biasc/stats
  ushort_t* vbf   = (ushort_t*)(ws);
  ushort_t* th    = (ushort_t*)(ws + 32 * MB);
  ushort_t* gvT   = (ushort_t*)(ws + 48 * MB);
  ushort_t* phT   = (ushort_t*)(ws + 64 * MB);
  ushort_t* Wy    = (ushort_t*)(ws + 48 * MB);
  float*    Mpart = (float*)(ws + 80 * MB);
  ushort_t* Qb    = (ushort_t*)(ws + 98 * MB);
  ushort_t* Wcat  = (ushort_t*)(ws + 102 * MB);
  ushort_t* Wwb   = (ushort_t*)(ws + 105 * MB);
  float* biasc    = (float*)(ws + 106 * MB);
  float* stats    = (float*)(ws + 106 * MB + 64 * 1024);

  // 1. prep: casts + weight packing + stats zero
  prep<<<24577, 256, 0, stream>>>(v, g_w, th_w, ph_w, W_w, g_b, th_b, ph_b,
                                  vbf, Wcat, Wwb, biasc, stats);

  // 2. GEMM1: projections; gv/ph written transposed via LDS bounce, th row-major
  gemm1<<<dim3(128, 12), 256, 0, stream>>>(vbf, Wcat, gvT, th, phT, biasc);

  // 3. GEMM2 split-K: M~[i][j] = (1/4096) sum_n ph[n][i] gv[n][j]  (fp32 partials)
  gemm_splitk<<<dim3(4, 8, 16), 256, 0, stream>>>(phT, gvT, Mpart);

  // 4. Q-GEMM (+fused partial reduce): Q[c][j] = sum_i Ww[c][i] * M~[j][i]
  gemm_q<<<dim3(16, 8, 4), 256, 0, stream>>>(Wwb, Mpart, Qb);

  // 5. GEMM3': Wy[n][c] = sum_j th[n][j] * Q[c][j] + W_b[c]  (+fused BN stats)
  gemm_bt<128, 128, true, true><<<dim3(32, 8, 4), 256, 0, stream>>>(
      th, Qb, Wy, W_b, 512, 512, 512, 1024,
      4096L * 512, 1024L * 512, 4096L * 1024, 1.0f, stats);

  // 6. BN finalize (inline) + apply + residual
  bn_apply<<<8192, 256, 0, stream>>>(Wy, vbf, stats, gamma, beta, out);
}

// Round 7
// 303.204 us; speedup vs baseline: 1.2636x; 1.0428x over previous
//
#include <hip/hip_runtime.h>
#include <stdint.h>

typedef unsigned short ushort_t;
typedef __attribute__((ext_vector_type(8))) short bf16x8;   // 8 bf16 in 4 VGPRs
typedef __attribute__((ext_vector_type(4))) float f32x4;

__device__ __forceinline__ float bf2f(unsigned short u) {
  return __uint_as_float(((unsigned)u) << 16);
}
__device__ __forceinline__ unsigned short f2bf(float f) {
  unsigned u = __float_as_uint(f);
  u += 0x7FFFu + ((u >> 16) & 1u);   // RNE
  return (unsigned short)(u >> 16);
}

__device__ __forceinline__ void gload_lds16(const ushort_t* g, ushort_t* l) {
  __builtin_amdgcn_global_load_lds(
      (__attribute__((address_space(1))) void*)(void*)g,
      (__attribute__((address_space(3))) void*)(void*)l, 16, 0, 0);
}

// ------------- merged: cast v->bf16 [0,16384) + pack weights [16384,24576) + stats-zero
__global__ void prep(const float* __restrict__ v,
                     const float* __restrict__ g_w, const float* __restrict__ th_w,
                     const float* __restrict__ ph_w, const float* __restrict__ W_w,
                     const float* __restrict__ g_b, const float* __restrict__ th_b,
                     const float* __restrict__ ph_b,
                     ushort_t* __restrict__ vbf,
                     ushort_t* __restrict__ Wcat, ushort_t* __restrict__ Ww,
                     float* __restrict__ bias_cat, float* __restrict__ stats) {
  if (blockIdx.x < 16384) {
    size_t i = ((size_t)blockIdx.x * 256 + threadIdx.x) * 4;
    float4 f = *(const float4*)(v + i);
    unsigned lo = (unsigned)f2bf(f.x) | (((unsigned)f2bf(f.y)) << 16);
    unsigned hi = (unsigned)f2bf(f.z) | (((unsigned)f2bf(f.w)) << 16);
    *(uint2*)(vbf + i) = make_uint2(lo, hi);
  } else if (blockIdx.x < 24576) {
    int i = (blockIdx.x - 16384) * 256 + threadIdx.x;
    if (i < 1536 * 1024) {
      int r = i >> 10;
      float val;
      if (r < 512)        val = g_w[i];
      else if (r < 1024)  val = th_w[i - 512 * 1024];
      else                val = ph_w[i - 1024 * 1024];
      Wcat[i] = f2bf(val);
    } else {
      int j = i - 1536 * 1024;
      Ww[j] = f2bf(W_w[j]);   // W_w is (1024, 512) row-major == B^T layout
    }
    if (i < 512)        bias_cat[i] = g_b[i];
    else if (i < 1024)  bias_cat[i] = th_b[i - 512];
    else if (i < 1536)  bias_cat[i] = ph_b[i - 1024];
  } else {
#pragma unroll
    for (int k = 0; k < 8; ++k) stats[threadIdx.x * 8 + k] = 0.f;
  }
}

// =====================================================================================
// 8-phase 256x256 GEMM (plain-HIP port of the m201 template).
// 512 thr = 8 waves (2M x 4N); BK=64 split in 2 k-halves; LDS [2buf][A,B][2kh][256][32].
// Stage: 1 half/phase (2 gload_lds/wave), counted vmcnt(4) at phases 4/8 (conservative-
// safe: every staged half has >=1 barrier of slack past its guaranteeing vmcnt).
// T2 swizzle: 16B-chunk ^= (row&3), applied on pre-swizzled global src + ds_read addr.
// EPI=0: gemm1 split epilogue (gvT/th/phT); EPI=1: row-major C + bias + BN stats.
// =====================================================================================
#define REG8(b, op, h) ((b) * 32768 + (op) * 16384 + (h) * 8192)

__device__ __forceinline__ void stage_half8(const ushort_t* __restrict__ G, int ld,
                                            int grow0, int kc0, ushort_t* dst,
                                            int wv, int lane) {
#pragma unroll
  for (int q = 0; q < 2; ++q) {
    int r = wv * 32 + q * 16 + (lane >> 2);
    int kc = ((lane & 3) ^ ((lane >> 2) & 3)) * 8;   // inverse-swizzled source chunk
    gload_lds16(G + (size_t)(grow0 + r) * ld + kc0 + kc,
                dst + wv * 1024 + q * 512 + lane * 8);   // linear LDS dest
  }
}

#define PHASE8(BB, HH, MU, DOB, STG, VMN)                                              \
  do {                                                                                 \
    const ushort_t* Ar_ = &lds[REG8(BB, 0, HH)] + baseA;                               \
    bf16x8 af0_ = *(const bf16x8*)(Ar_ + ((MU)*4 + 0) * 512);                          \
    bf16x8 af1_ = *(const bf16x8*)(Ar_ + ((MU)*4 + 1) * 512);                          \
    bf16x8 af2_ = *(const bf16x8*)(Ar_ + ((MU)*4 + 2) * 512);                          \
    bf16x8 af3_ = *(const bf16x8*)(Ar_ + ((MU)*4 + 3) * 512);                          \
    if (DOB) {                                                                         \
      const ushort_t* Br_ = &lds[REG8(BB, 1, HH)] + baseB;                             \
      bfr0 = *(const bf16x8*)(Br_ + 0 * 512);                                          \
      bfr1 = *(const bf16x8*)(Br_ + 1 * 512);                                          \
      bfr2 = *(const bf16x8*)(Br_ + 2 * 512);                                          \
      bfr3 = *(const bf16x8*)(Br_ + 3 * 512);                                          \
    }                                                                                  \
    STG;                                                                               \
    if ((VMN) == 4) asm volatile("s_waitcnt vmcnt(4)" ::: "memory");                   \
    if ((VMN) == 0) asm volatile("s_waitcnt vmcnt(0)" ::: "memory");                   \
    __builtin_amdgcn_s_barrier();                                                      \
    asm volatile("s_waitcnt lgkmcnt(0)" ::: "memory");                                 \
    __builtin_amdgcn_sched_barrier(0);                                                 \
    __builtin_amdgcn_s_setprio(1);                                                     \
    acc[(MU)*4 + 0][0] = __builtin_amdgcn_mfma_f32_16x16x32_bf16(af0_, bfr0, acc[(MU)*4 + 0][0], 0, 0, 0); \
    acc[(MU)*4 + 0][1] = __builtin_amdgcn_mfma_f32_16x16x32_bf16(af0_, bfr1, acc[(MU)*4 + 0][1], 0, 0, 0); \
    acc[(MU)*4 + 0][2] = __builtin_amdgcn_mfma_f32_16x16x32_bf16(af0_, bfr2, acc[(MU)*4 + 0][2], 0, 0, 0); \
    acc[(MU)*4 + 0][3] = __builtin_amdgcn_mfma_f32_16x16x32_bf16(af0_, bfr3, acc[(MU)*4 + 0][3], 0, 0, 0); \
    acc[(MU)*4 + 1][0] = __builtin_amdgcn_mfma_f32_16x16x32_bf16(af1_, bfr0, acc[(MU)*4 + 1][0], 0, 0, 0); \
    acc[(MU)*4 + 1][1] = __builtin_amdgcn_mfma_f32_16x16x32_bf16(af1_, bfr1, acc[(MU)*4 + 1][1], 0, 0, 0); \
    acc[(MU)*4 + 1][2] = __builtin_amdgcn_mfma_f32_16x16x32_bf16(af1_, bfr2, acc[(MU)*4 + 1][2], 0, 0, 0); \
    acc[(MU)*4 + 1][3] = __builtin_amdgcn_mfma_f32_16x16x32_bf16(af1_, bfr3, acc[(MU)*4 + 1][3], 0, 0, 0); \
    acc[(MU)*4 + 2][0] = __builtin_amdgcn_mfma_f32_16x16x32_bf16(af2_, bfr0, acc[(MU)*4 + 2][0], 0, 0, 0); \
    acc[(MU)*4 + 2][1] = __builtin_amdgcn_mfma_f32_16x16x32_bf16(af2_, bfr1, acc[(MU)*4 + 2][1], 0, 0, 0); \
    acc[(MU)*4 + 2][2] = __builtin_amdgcn_mfma_f32_16x16x32_bf16(af2_, bfr2, acc[(MU)*4 + 2][2], 0, 0, 0); \
    acc[(MU)*4 + 2][3] = __builtin_amdgcn_mfma_f32_16x16x32_bf16(af2_, bfr3, acc[(MU)*4 + 2][3], 0, 0, 0); \
    acc[(MU)*4 + 3][0] = __builtin_amdgcn_mfma_f32_16x16x32_bf16(af3_, bfr0, acc[(MU)*4 + 3][0], 0, 0, 0); \
    acc[(MU)*4 + 3][1] = __builtin_amdgcn_mfma_f32_16x16x32_bf16(af3_, bfr1, acc[(MU)*4 + 3][1], 0, 0, 0); \
    acc[(MU)*4 + 3][2] = __builtin_amdgcn_mfma_f32_16x16x32_bf16(af3_, bfr2, acc[(MU)*4 + 3][2], 0, 0, 0); \
    acc[(MU)*4 + 3][3] = __builtin_amdgcn_mfma_f32_16x16x32_bf16(af3_, bfr3, acc[(MU)*4 + 3][3], 0, 0, 0); \
    __builtin_amdgcn_s_setprio(0);                                                     \
    __builtin_amdgcn_sched_barrier(0);                                                 \
    __builtin_amdgcn_s_barrier();                                                      \
  } while (0)

template <int NT, int EPI>
__global__ __launch_bounds__(512, 1) void gemm8(
    const ushort_t* __restrict__ A, const ushort_t* __restrict__ B,
    ushort_t* __restrict__ C0, ushort_t* __restrict__ th, ushort_t* __restrict__ phT,
    const float* __restrict__ bias, float* __restrict__ stats,
    int lda, int ldb, int ldc, long sA, long sB, long sC) {
  __shared__ ushort_t lds[65536];   // 128 KiB
  const int tid = threadIdx.x;
  const int lane = tid & 63;
  const int wv = tid >> 6;
  const int wr = wv >> 2, wc = wv & 3;
  const int tm0 = blockIdx.x * 256;
  const int tn0 = blockIdx.y * 256;
  const long bz = blockIdx.z;
  A += bz * sA;
  B += bz * sB;

  f32x4 acc[8][4] = {};
  const int baseA = ((wr << 7) + (lane & 15)) * 32 + (((lane >> 4) ^ (lane & 3)) << 3);
  const int baseB = ((wc << 6) + (lane & 15)) * 32 + (((lane >> 4) ^ (lane & 3)) << 3);
  bf16x8 bfr0, bfr1, bfr2, bfr3;

  // prologue: T0 fully, T1 k0; drain once.
  stage_half8(A, lda, tm0, 0,  &lds[REG8(0, 0, 0)], wv, lane);
  stage_half8(A, lda, tm0, 32, &lds[REG8(0, 0, 1)], wv, lane);
  stage_half8(B, ldb, tn0, 0,  &lds[REG8(0, 1, 0)], wv, lane);
  stage_half8(B, ldb, tn0, 32, &lds[REG8(0, 1, 1)], wv, lane);
  stage_half8(A, lda, tm0, 64, &lds[REG8(1, 0, 0)], wv, lane);
  stage_half8(B, ldb, tn0, 64, &lds[REG8(1, 1, 0)], wv, lane);
  asm volatile("s_waitcnt vmcnt(0)" ::: "memory");
  __builtin_amdgcn_s_barrier();

  const int FULL = NT / 2 - 1;
  for (int i = 0; i < FULL; ++i) {
    const int k1 = (2 * i + 1) * 64 + 32;
    const int k2 = (2 * i + 2) * 64;
    const int k3 = (2 * i + 3) * 64;
    PHASE8(0, 0, 0, true,  stage_half8(A, lda, tm0, k1,      &lds[REG8(1, 0, 1)], wv, lane), -1);
    PHASE8(0, 0, 1, false, stage_half8(B, ldb, tn0, k1,      &lds[REG8(1, 1, 1)], wv, lane), -1);
    PHASE8(0, 1, 0, true,  stage_half8(A, lda, tm0, k2,      &lds[REG8(0, 0, 0)], wv, lane), -1);
    PHASE8(0, 1, 1, false, stage_half8(B, ldb, tn0, k2,      &lds[REG8(0, 1, 0)], wv, lane), 4);
    PHASE8(1, 0, 0, true,  stage_half8(A, lda, tm0, k2 + 32, &lds[REG8(0, 0, 1)], wv, lane), -1);
    PHASE8(1, 0, 1, false, stage_half8(B, ldb, tn0, k2 + 32, &lds[REG8(0, 1, 1)], wv, lane), -1);
    PHASE8(1, 1, 0, true,  stage_half8(A, lda, tm0, k3,      &lds[REG8(1, 0, 0)], wv, lane), -1);
    PHASE8(1, 1, 1, false, stage_half8(B, ldb, tn0, k3,      &lds[REG8(1, 1, 0)], wv, lane), 4);
  }
  {  // final iteration: stage only T(NT-1).k1, drain at P4.
    const int k1 = (NT - 1) * 64 + 32;
    PHASE8(0, 0, 0, true,  stage_half8(A, lda, tm0, k1, &lds[REG8(1, 0, 1)], wv, lane), -1);
    PHASE8(0, 0, 1, false, stage_half8(B, ldb, tn0, k1, &lds[REG8(1, 1, 1)], wv, lane), -1);
    PHASE8(0, 1, 0, true,  (void)0, -1);
    PHASE8(0, 1, 1, false, (void)0, 0);
    PHASE8(1, 0, 0, true,  (void)0, -1);
    PHASE8(1, 0, 1, false, (void)0, -1);
    PHASE8(1, 1, 0, true,  (void)0, -1);
    PHASE8(1, 1, 1, false, (void)0, -1);
  }

  if (EPI == 1) {
    // row-major C + bias + BN column stats
    ushort_t* C = C0 + bz * sC;
#pragma unroll
    for (int nf = 0; nf < 4; ++nf) {
      const int col = tn0 + wc * 64 + nf * 16 + (lane & 15);
      const float bv = bias[col];
      float s = 0.f, s2 = 0.f;
#pragma unroll
      for (int mf = 0; mf < 8; ++mf) {
#pragma unroll
        for (int r = 0; r < 4; ++r) {
          const int row = tm0 + wr * 128 + mf * 16 + (lane >> 4) * 4 + r;
          float val = acc[mf][nf][r] + bv;
          C[(size_t)row * ldc + col] = f2bf(val);
          s += val; s2 += val * val;
        }
      }
      s  += __shfl_xor(s, 16);  s  += __shfl_xor(s, 32);
      s2 += __shfl_xor(s2, 16); s2 += __shfl_xor(s2, 32);
      if ((lane >> 4) == 0) {
        atomicAdd(&stats[col], s);
        atomicAdd(&stats[1024 + col], s2);
      }
    }
  } else {
    // gemm1 split epilogue: y in {2,3} -> th row-major; else transposed via LDS bounce
    const int yb = blockIdx.y;
    if (yb == 2 || yb == 3) {
#pragma unroll
      for (int nf = 0; nf < 4; ++nf) {
        const int gcol = tn0 + wc * 64 + nf * 16 + (lane & 15);
        const float bv = bias[gcol];
        const int col = gcol - 512;
#pragma unroll
        for (int mf = 0; mf < 8; ++mf) {
#pragma unroll
          for (int r = 0; r < 4; ++r) {
            const int row = tm0 + wr * 128 + mf * 16 + (lane >> 4) * 4 + r;
            th[(size_t)row * 512 + col] = f2bf(acc[mf][nf][r] + bv);
          }
        }
      }
    } else {
      ushort_t* T = (yb < 2) ? C0 : phT;
      const int cbase = (yb < 2) ? tn0 : tn0 - 1024;
      const int bq = tm0 >> 12;
      const int npb = tm0 & 4095;
      float bvv[4];
#pragma unroll
      for (int nf = 0; nf < 4; ++nf) bvv[nf] = bias[tn0 + wc * 64 + nf * 16 + (lane & 15)];
#pragma unroll
      for (int cg = 0; cg < 4; ++cg) {
        __syncthreads();
        if (wc == cg) {
#pragma unroll
          for (int mf = 0; mf < 8; ++mf) {
            const int n0 = wr * 128 + mf * 16 + (lane >> 4) * 4;
#pragma unroll
            for (int nf = 0; nf < 4; ++nf) {
              const int c = nf * 16 + (lane & 15);
              unsigned lo = (unsigned)f2bf(acc[mf][nf][0] + bvv[nf]) |
                            (((unsigned)f2bf(acc[mf][nf][1] + bvv[nf])) << 16);
              unsigned hi = (unsigned)f2bf(acc[mf][nf][2] + bvv[nf]) |
                            (((unsigned)f2bf(acc[mf][nf][3] + bvv[nf])) << 16);
              *(uint2*)&lds[c * 264 + n0] = make_uint2(lo, hi);
            }
          }
        }
        __syncthreads();
#pragma unroll
        for (int rd = 0; rd < 4; ++rd) {
          const int idx = rd * 512 + tid;
          const int c = idx >> 5, ns = idx & 31;
          bf16x8 val = *(const bf16x8*)&lds[c * 264 + ns * 8];
          *(bf16x8*)(T + ((size_t)(bq * 512 + cbase + cg * 64 + c)) * 4096 + npb + ns * 8) = val;
        }
      }
    }
  }
}

// ---------------- split-K GEMM2: Mpart[b*4+kc][i][j] (fp32, pre-scaled 1/4096) ------
__global__ __launch_bounds__(256) void gemm_splitk(
    const ushort_t* __restrict__ A, const ushort_t* __restrict__ B,
    float* __restrict__ Cp) {
  constexpr int BM = 128, BN = 64, FR_M = 4, FR_N = 2;
  __shared__ ushort_t As[BM * 64];
  __shared__ ushort_t Bs[BN * 64];
  const int tid = threadIdx.x;
  const int lane = tid & 63;
  const int wm = tid >> 7;
  const int wn = (tid >> 6) & 1;
  const int b = blockIdx.z >> 2, kc = blockIdx.z & 3;
  const ushort_t* Ab = A + (size_t)b * 512 * 4096 + kc * 1024;
  const ushort_t* Bb = B + (size_t)b * 512 * 4096 + kc * 1024;
  float* Cb = Cp + (size_t)blockIdx.z * 512 * 512;
  const int tm0 = blockIdx.x * BM, tn0 = blockIdx.y * BN;

  f32x4 acc[FR_M][FR_N] = {};

  for (int kt = 0; kt < 1024; kt += 64) {
#pragma unroll
    for (int it = 0; it < BM / 32; ++it) {
      int g = it * 256 + tid;
      gload_lds16(Ab + (long)(tm0 + (g >> 3)) * 4096 + kt + (g & 7) * 8, &As[g * 8]);
    }
#pragma unroll
    for (int it = 0; it < BN / 32; ++it) {
      int g = it * 256 + tid;
      gload_lds16(Bb + (long)(tn0 + (g >> 3)) * 4096 + kt + (g & 7) * 8, &Bs[g * 8]);
    }
    __syncthreads();
#pragma unroll
    for (int kk = 0; kk < 2; ++kk) {
      bf16x8 af[FR_M], bfr[FR_N];
#pragma unroll
      for (int m = 0; m < FR_M; ++m)
        af[m] = *(const bf16x8*)&As[(wm * (BM / 2) + m * 16 + (lane & 15)) * 64 +
                                    kk * 32 + (lane >> 4) * 8];
#pragma unroll
      for (int n = 0; n < FR_N; ++n)
        bfr[n] = *(const bf16x8*)&Bs[(wn * (BN / 2) + n * 16 + (lane & 15)) * 64 +
                                     kk * 32 + (lane >> 4) * 8];
#pragma unroll
      for (int m = 0; m < FR_M; ++m)
#pragma unroll
        for (int n = 0; n < FR_N; ++n)
          acc[m][n] = __builtin_amdgcn_mfma_f32_16x16x32_bf16(af[m], bfr[n], acc[m][n], 0, 0, 0);
    }
    __syncthreads();
  }

#pragma unroll
  for (int m = 0; m < FR_M; ++m)
#pragma unroll
    for (int n = 0; n < FR_N; ++n) {
      const int col = tn0 + wn * (BN / 2) + n * 16 + (lane & 15);
#pragma unroll
      for (int r = 0; r < 4; ++r) {
        const int row = tm0 + wm * (BM / 2) + m * 16 + (lane >> 4) * 4 + r;
        Cb[(long)row * 512 + col] = (1.0f / 4096.0f) * acc[m][n][r];
      }
    }
}

// ---------------- Q-GEMM with fused partial-reduce on the B operand -----------------
// Q[b][c][j] = sum_i Ww[c][i] * M[b][j][i],  M = sum of 4 fp32 partials (bf16-rounded)
__global__ __launch_bounds__(256) void gemm_q(
    const ushort_t* __restrict__ Ww, const float* __restrict__ Mpart,
    ushort_t* __restrict__ Qb) {
  __shared__ ushort_t As[64 * 64];
  __shared__ ushort_t Bs[64 * 64];
  const int tid = threadIdx.x;
  const int lane = tid & 63;
  const int wm = tid >> 7;
  const int wn = (tid >> 6) & 1;
  const int b = blockIdx.z;
  const float* Mb4 = Mpart + (size_t)b * 4 * 262144;
  ushort_t* Cb = Qb + (size_t)b * 1024 * 512;
  const int tm0 = blockIdx.x * 64, tn0 = blockIdx.y * 64;

  f32x4 acc[2][2] = {};

  for (int kt = 0; kt < 512; kt += 64) {
#pragma unroll
    for (int it = 0; it < 2; ++it) {
      int g = it * 256 + tid;
      gload_lds16(Ww + (long)(tm0 + (g >> 3)) * 512 + kt + (g & 7) * 8, &As[g * 8]);
    }
#pragma unroll
    for (int it = 0; it < 2; ++it) {
      int g = it * 256 + tid;
      const int jr = g >> 3, ioff = (g & 7) * 8;
      const float* src = Mb4 + (size_t)(tn0 + jr) * 512 + kt + ioff;
      float4 s0 = *(const float4*)(src);
      float4 s1 = *(const float4*)(src + 4);
#pragma unroll
      for (int p = 1; p < 4; ++p) {
        float4 t0 = *(const float4*)(src + (size_t)p * 262144);
        float4 t1 = *(const float4*)(src + (size_t)p * 262144 + 4);
        s0.x += t0.x; s0.y += t0.y; s0.z += t0.z; s0.w += t0.w;
        s1.x += t1.x; s1.y += t1.y; s1.z += t1.z; s1.w += t1.w;
      }
      bf16x8 o;
      o[0] = (short)f2bf(s0.x); o[1] = (short)f2bf(s0.y);
      o[2] = (short)f2bf(s0.z); o[3] = (short)f2bf(s0.w);
      o[4] = (short)f2bf(s1.x); o[5] = (short)f2bf(s1.y);
      o[6] = (short)f2bf(s1.z); o[7] = (short)f2bf(s1.w);
      *(bf16x8*)&Bs[g * 8] = o;
    }
    __syncthreads();
#pragma unroll
    for (int kk = 0; kk < 2; ++kk) {
      bf16x8 af[2], bfr[2];
#pragma unroll
      for (int m = 0; m < 2; ++m)
        af[m] = *(const bf16x8*)&As[(wm * 32 + m * 16 + (lane & 15)) * 64 +
                                    kk * 32 + (lane >> 4) * 8];
#pragma unroll
      for (int n = 0; n < 2; ++n)
        bfr[n] = *(const bf16x8*)&Bs[(wn * 32 + n * 16 + (lane & 15)) * 64 +
                                     kk * 32 + (lane >> 4) * 8];
#pragma unroll
      for (int m = 0; m < 2; ++m)
#pragma unroll
        for (int n = 0; n < 2; ++n)
          acc[m][n] = __builtin_amdgcn_mfma_f32_16x16x32_bf16(af[m], bfr[n], acc[m][n], 0, 0, 0);
    }
    __syncthreads();
  }

#pragma unroll
  for (int m = 0; m < 2; ++m)
#pragma unroll
    for (int n = 0; n < 2; ++n) {
      const int col = tn0 + wn * 32 + n * 16 + (lane & 15);
#pragma unroll
      for (int r = 0; r < 4; ++r) {
        const int row = tm0 + wm * 32 + m * 16 + (lane >> 4) * 4 + r;
        Cb[(long)row * 512 + col] = f2bf(acc[m][n][r]);
      }
    }
}

// ---------------- apply BN (inline finalize) + residual (bf16 v) --------------------
__global__ void bn_apply(const ushort_t* __restrict__ Wy, const ushort_t* __restrict__ vbf,
                         const float* __restrict__ stats, const float* __restrict__ gamma,
                         const float* __restrict__ beta, float* __restrict__ out) {
  __shared__ float scsh[2048];
  const int t = threadIdx.x;
#pragma unroll
  for (int k = 0; k < 4; ++k) {
    int c = t * 4 + k;
    float mean = stats[c] * (1.0f / 16384.0f);
    float var = stats[1024 + c] * (1.0f / 16384.0f) - mean * mean;
    float sc = gamma[c] * rsqrtf(var + 1e-5f);
    scsh[c] = sc;
    scsh[1024 + c] = beta[c] - mean * sc;
  }
  __syncthreads();
  size_t i = ((size_t)blockIdx.x * 256 + t) * 8;
  int c0 = (int)(i & 1023);
  bf16x8 w = *(const bf16x8*)(Wy + i);
  bf16x8 vv = *(const bf16x8*)(vbf + i);
  float4 o0, o1;
  o0.x = bf2f((unsigned short)w[0]) * scsh[c0 + 0] + scsh[1024 + c0 + 0] + bf2f((unsigned short)vv[0]);
  o0.y = bf2f((unsigned short)w[1]) * scsh[c0 + 1] + scsh[1024 + c0 + 1] + bf2f((unsigned short)vv[1]);
  o0.z = bf2f((unsigned short)w[2]) * scsh[c0 + 2] + scsh[1024 + c0 + 2] + bf2f((unsigned short)vv[2]);
  o0.w = bf2f((unsigned short)w[3]) * scsh[c0 + 3] + scsh[1024 + c0 + 3] + bf2f((unsigned short)vv[3]);
  o1.x = bf2f((unsigned short)w[4]) * scsh[c0 + 4] + scsh[1024 + c0 + 4] + bf2f((unsigned short)vv[4]);
  o1.y = bf2f((unsigned short)w[5]) * scsh[c0 + 5] + scsh[1024 + c0 + 5] + bf2f((unsigned short)vv[5]);
  o1.z = bf2f((unsigned short)w[6]) * scsh[c0 + 6] + scsh[1024 + c0 + 6] + bf2f((unsigned short)vv[6]);
  o1.w = bf2f((unsigned short)w[7]) * scsh[c0 + 7] + scsh[1024 + c0 + 7] + bf2f((unsigned short)vv[7]);
  *(float4*)(out + i) = o0;
  *(float4*)(out + i + 4) = o1;
}

extern "C" void kernel_launch(void* const* d_in, const int* in_sizes, int n_in,
                              void* d_out, int out_size, void* d_ws, size_t ws_size,
                              hipStream_t stream) {
  const float* v     = (const float*)d_in[0];
  const float* g_w   = (const float*)d_in[1];
  const float* g_b   = (const float*)d_in[2];
  const float* th_w  = (const float*)d_in[3];
  const float* th_b  = (const float*)d_in[4];
  const float* ph_w  = (const float*)d_in[5];
  const float* ph_b  = (const float*)d_in[6];
  const float* W_w   = (const float*)d_in[7];
  const float* W_b   = (const float*)d_in[8];
  const float* gamma = (const float*)d_in[9];
  const float* beta  = (const float*)d_in[10];
  float* out = (float*)d_out;
  char* ws = (char*)d_ws;

  const size_t MB = 1024 * 1024;
  ushort_t* vbf   = (ushort_t*)(ws);
  ushort_t* th    = (ushort_t*)(ws + 32 * MB);
  ushort_t* gvT   = (ushort_t*)(ws + 48 * MB);
  ushort_t* phT   = (ushort_t*)(ws + 64 * MB);
  ushort_t* Wy    = (ushort_t*)(ws + 48 * MB);
  float*    Mpart = (float*)(ws + 80 * MB);
  ushort_t* Qb    = (ushort_t*)(ws + 98 * MB);
  ushort_t* Wcat  = (ushort_t*)(ws + 102 * MB);
  ushort_t* Wwb   = (ushort_t*)(ws + 105 * MB);
  float* biasc    = (float*)(ws + 106 * MB);
  float* stats    = (float*)(ws + 106 * MB + 64 * 1024);

  // 1. prep: casts + weight packing + stats zero
  prep<<<24577, 256, 0, stream>>>(v, g_w, th_w, ph_w, W_w, g_b, th_b, ph_b,
                                  vbf, Wcat, Wwb, biasc, stats);

  // 2. GEMM1 (8-phase): projections; gv/ph transposed via bounce, th row-major
  gemm8<16, 0><<<dim3(64, 6, 1), 512, 0, stream>>>(
      vbf, Wcat, gvT, th, phT, biasc, nullptr, 1024, 1024, 0, 0L, 0L, 0L);

  // 3. GEMM2 split-K: M~[i][j] = (1/4096) sum_n ph[n][i] gv[n][j]  (fp32 partials)
  gemm_splitk<<<dim3(4, 8, 16), 256, 0, stream>>>(phT, gvT, Mpart);

  // 4. Q-GEMM (+fused partial reduce): Q[c][j] = sum_i Ww[c][i] * M~[j][i]
  gemm_q<<<dim3(16, 8, 4), 256, 0, stream>>>(Wwb, Mpart, Qb);

  // 5. GEMM3' (8-phase): Wy[n][c] = sum_j th[n][j] * Q[c][j] + W_b[c]  (+BN stats)
  gemm8<8, 1><<<dim3(16, 4, 4), 512, 0, stream>>>(
      th, Qb, Wy, nullptr, nullptr, W_b, stats, 512, 512, 1024,
      4096L * 512, 1024L * 512, 4096L * 1024);

  // 6. BN finalize (inline) + apply + residual
  bn_apply<<<8192, 256, 0, stream>>>(Wy, vbf, stats, gamma, beta, out);
}